// Round 6
// baseline (104.051 us; speedup 1.0000x reference)
//
#include <hip/hip_runtime.h>
#include <math.h>

#define NTHR 256
#define MAXBLK 4096

// ws layout: [0, MAXBLK*8) double partials; [MAXBLK*8, ...) float4 pts
// pts[p] = (z0x, z0y, v0x, v0y)

__global__ void pack_kernel(const float* __restrict__ z0,
                            const float* __restrict__ v0,
                            float4* __restrict__ pts, int n_pts) {
    int p = blockIdx.x * blockDim.x + threadIdx.x;
    if (p < n_pts)
        pts[p] = make_float4(z0[2 * p], z0[2 * p + 1], v0[2 * p], v0[2 * p + 1]);
}

// signed erf tail: sgn(x) * P(t(|x|)) * exp2(eL - x^2*log2e)
// (A&S 7.1.26: erf(x) = sgn(x)*(1 - P*exp(-x^2)), |err| <= 1.5e-7)
// HW-verified R3/R4/R5 (absmax 0.0 vs np reference). DO NOT TOUCH.
__device__ __forceinline__ float erf_term(float x, float eL) {
    const float L2E = 1.4426950408889634f;
    float ax = fabsf(x);
    float tt = __builtin_amdgcn_rcpf(fmaf(0.3275911f, ax, 1.0f));
    float P = tt * fmaf(tt, fmaf(tt, fmaf(tt, fmaf(tt, 1.061405429f, -1.453152027f),
                        1.421413741f), -0.284496736f), 0.254829592f);
    float arg = fmaf(x * L2E, -x, eL);
    return copysignf(P * __builtin_amdgcn_exp2f(arg), x);
}

// integral term for one (i,j) pair; pref*exp folded into erf tails.
__device__ __forceinline__ float pair_val(float4 Pi, float4 Pj,
                                          float b, float t0, float tn) {
    const float SPI2 = 0.88622692545275801365f;  // sqrt(pi)/2
    const float L2E  = 1.4426950408889634f;
    float dzx = Pi.x - Pj.x, dzy = Pi.y - Pj.y;
    float dvx = Pi.z - Pj.z, dvy = Pi.w - Pj.w;
    float a2 = fmaf(dzx, dzx, dzy * dzy);
    float b2 = fmaf(dvx, dvx, dvy * dvy);
    float ab = fmaf(dzx, dvx, dzy * dvy);
    float r  = __builtin_amdgcn_rsqf(b2);      // 1/bnorm
    float mu = ab * (r * r);
    float e0 = fmaf(ab, mu, b - a2);           // in [b-a2, b] — exp never overflows
    float eL = e0 * L2E;
    float bn = b2 * r;
    float x1 = bn * (tn + mu);
    float x0 = bn * (t0 + mu);
    float pe1 = erf_term(x1, eL);
    float pe0 = erf_term(x0, eL);
    float jump = (x0 < 0.f && x1 >= 0.f)
                     ? 2.f * __builtin_amdgcn_exp2f(eL) : 0.f;
    return (SPI2 * r) * (jump + pe0 - pe1);
}

__global__ __launch_bounds__(NTHR) void cvm_main_kernel(
    const int2* __restrict__ idx, const float* __restrict__ t,
    const float4* __restrict__ pts,
    const float* __restrict__ t0p, const float* __restrict__ tnp,
    const float* __restrict__ betap,
    int n_events, int n_pts, double* __restrict__ partials) {

    const float b  = betap[0];
    const float t0 = t0p[0];
    const float tn = tnp[0];
    const int nblocks = gridDim.x;

    float accf = 0.0f;  // Sum(d_event) + Sum(integral); final = N*b - total

    // ---- Event part: grid-stride, coalesced idx/t stream, float4 gathers
    for (int e = blockIdx.x * NTHR + threadIdx.x; e < n_events;
         e += nblocks * NTHR) {
        int2 ij  = idx[e];
        float te = t[e];
        float4 pi = pts[ij.x];
        float4 pj = pts[ij.y];
        float dx = (pi.x - pj.x) + (pi.z - pj.z) * te;
        float dy = (pi.y - pj.y) + (pi.w - pj.w) * te;
        accf = fmaf(dx, dx, fmaf(dy, dy, accf));
    }

    // ---- Pair part: block b owns 4 rows — adjacent {2b, 2b+1} (bottom) and
    // adjacent-complementary {nrows-2-2b, nrows-1-2b} (top). Per-block pair
    // count = 2*nrows+4 = const (balanced). ONE pts[j] load feeds up to 4
    // independent pair-chains (math:load 4x, ILP 4). The j>r2 region is
    // wave-uniform-false for the first part of the sweep -> execz-skipped.
    // Coverage (n_rows=4999): A covers 0..2499; B covers 2501..4998 (b<=1248)
    // + row 2500 (b=1249, where r2==r1 is guarded off). No dups.
    const int n_rows = n_pts - 1;          // rows 0..n_pts-2 hold pairs
    const int r0 = 2 * blockIdx.x;
    if (r0 < n_rows) {
        const int r1 = r0 + 1;
        const int r2 = (n_rows - 2) - r0;
        const int r3 = (n_rows - 1) - r0;
        const bool has1 = (r1 < n_rows);
        const bool has2 = (r2 > r1);
        const bool has3 = (r3 > r1);
        const float4 P0 = pts[r0];
        const float4 P1 = pts[min(r1, n_rows - 1)];
        const float4 P2 = pts[max(r2, 0)];
        const float4 P3 = pts[max(r3, 0)];

        for (int j = r0 + 1 + threadIdx.x; j < n_pts; j += NTHR) {
            float4 Pj = pts[j];                        // coalesced, shared by 4 rows
            accf += pair_val(P0, Pj, b, t0, tn);       // j > r0 always here
            if (has1 && j > r1)
                accf += pair_val(P1, Pj, b, t0, tn);
            if (j > r2) {                              // execz-skips early sweep
                if (has2)
                    accf += pair_val(P2, Pj, b, t0, tn);
                if (has3 && j > r3)
                    accf += pair_val(P3, Pj, b, t0, tn);
            }
        }
    }

    // ---- Block reduce (double), plain store — no atomics, no fences
    double v = (double)accf;
    #pragma unroll
    for (int off = 32; off > 0; off >>= 1) v += __shfl_down(v, off, 64);
    __shared__ double wsum[4];
    if ((threadIdx.x & 63) == 0) wsum[threadIdx.x >> 6] = v;
    __syncthreads();
    if (threadIdx.x == 0)
        partials[blockIdx.x] = wsum[0] + wsum[1] + wsum[2] + wsum[3];
}

__global__ void finish_kernel(const double* __restrict__ partials, int nblk,
                              const float* __restrict__ betap,
                              float* __restrict__ out, int n_events) {
    double v = 0.0;
    for (int i = threadIdx.x; i < nblk; i += NTHR) v += partials[i];
    #pragma unroll
    for (int off = 32; off > 0; off >>= 1) v += __shfl_down(v, off, 64);
    __shared__ double wsum[4];
    if ((threadIdx.x & 63) == 0) wsum[threadIdx.x >> 6] = v;
    __syncthreads();
    if (threadIdx.x == 0)
        out[0] = (float)((double)n_events * (double)betap[0] -
                         (wsum[0] + wsum[1] + wsum[2] + wsum[3]));
}

extern "C" void kernel_launch(void* const* d_in, const int* in_sizes, int n_in,
                              void* d_out, int out_size, void* d_ws, size_t ws_size,
                              hipStream_t stream) {
    const int2*  idx  = (const int2*)d_in[0];
    const float* t    = (const float*)d_in[1];
    const float* t0   = (const float*)d_in[2];
    const float* tn   = (const float*)d_in[3];
    const float* z0   = (const float*)d_in[4];
    const float* v0   = (const float*)d_in[5];
    const float* beta = (const float*)d_in[6];
    const int n_events = in_sizes[1];
    const int n_pts    = in_sizes[4] / 2;

    double* partials = (double*)d_ws;
    float4* pts = (float4*)((char*)d_ws + MAXBLK * sizeof(double));

    const int n_rows = n_pts - 1;          // 4999
    int nblk = (n_rows + 3) / 4;           // 1250: 4 rows per block
    if (nblk < 1) nblk = 1;
    if (nblk > MAXBLK) nblk = MAXBLK;

    pack_kernel<<<(n_pts + NTHR - 1) / NTHR, NTHR, 0, stream>>>(z0, v0, pts, n_pts);
    cvm_main_kernel<<<nblk, NTHR, 0, stream>>>(idx, t, pts, t0, tn, beta,
                                               n_events, n_pts, partials);
    finish_kernel<<<1, NTHR, 0, stream>>>(partials, nblk, beta,
                                          (float*)d_out, n_events);
}

// Round 7
// 102.345 us; speedup vs baseline: 1.0167x; 1.0167x over previous
//
#include <hip/hip_runtime.h>
#include <math.h>

#define NTHR 256
#define MAXBLK 4096

// ws layout: [0, MAXBLK*8) double partials; [MAXBLK*8, ...) float4 pts
// pts[p] = (z0x, z0y, v0x, v0y)

__global__ void pack_kernel(const float* __restrict__ z0,
                            const float* __restrict__ v0,
                            float4* __restrict__ pts, int n_pts) {
    int p = blockIdx.x * blockDim.x + threadIdx.x;
    if (p < n_pts)
        pts[p] = make_float4(z0[2 * p], z0[2 * p + 1], v0[2 * p], v0[2 * p + 1]);
}

// signed erf tail: sgn(x) * P(t(|x|)) * exp2(eL - x^2*log2e)
// (A&S 7.1.26: erf(x) = sgn(x)*(1 - P*exp(-x^2)), |err| <= 1.5e-7)
// HW-verified R3-R6 (absmax 0.0 vs np reference). DO NOT TOUCH.
__device__ __forceinline__ float erf_term(float x, float eL) {
    const float L2E = 1.4426950408889634f;
    float ax = fabsf(x);
    float tt = __builtin_amdgcn_rcpf(fmaf(0.3275911f, ax, 1.0f));
    float P = tt * fmaf(tt, fmaf(tt, fmaf(tt, fmaf(tt, 1.061405429f, -1.453152027f),
                        1.421413741f), -0.284496736f), 0.254829592f);
    float arg = fmaf(x * L2E, -x, eL);
    return copysignf(P * __builtin_amdgcn_exp2f(arg), x);
}

// integral term for one (i,j) pair; pref*exp folded into erf tails.
__device__ __forceinline__ float pair_val(float4 Pi, float4 Pj,
                                          float b, float t0, float tn) {
    const float SPI2 = 0.88622692545275801365f;  // sqrt(pi)/2
    const float L2E  = 1.4426950408889634f;
    float dzx = Pi.x - Pj.x, dzy = Pi.y - Pj.y;
    float dvx = Pi.z - Pj.z, dvy = Pi.w - Pj.w;
    float a2 = fmaf(dzx, dzx, dzy * dzy);
    float b2 = fmaf(dvx, dvx, dvy * dvy);
    float ab = fmaf(dzx, dvx, dzy * dvy);
    float r  = __builtin_amdgcn_rsqf(b2);      // 1/bnorm
    float mu = ab * (r * r);
    float e0 = fmaf(ab, mu, b - a2);           // in [b-a2, b] — exp never overflows
    float eL = e0 * L2E;
    float bn = b2 * r;
    float x1 = bn * (tn + mu);
    float x0 = bn * (t0 + mu);
    float pe1 = erf_term(x1, eL);
    float pe0 = erf_term(x0, eL);
    float jump = (x0 < 0.f && x1 >= 0.f)
                     ? 2.f * __builtin_amdgcn_exp2f(eL) : 0.f;
    return (SPI2 * r) * (jump + pe0 - pe1);
}

// j-sweep for one row: 2-way unrolled, both loads issued before either math
// chain (load-use distance spans ~90 cycles of independent math; ILP=2).
__device__ __forceinline__ float row_sweep(const float4* __restrict__ pts,
                                           float4 Pi, int jstart, int n_pts,
                                           float b, float t0, float tn) {
    float acc = 0.0f;
    int j = jstart + threadIdx.x;
    for (; j + NTHR < n_pts; j += 2 * NTHR) {
        float4 Pj0 = pts[j];            // both loads in flight before any use
        float4 Pj1 = pts[j + NTHR];
        acc += pair_val(Pi, Pj0, b, t0, tn);
        acc += pair_val(Pi, Pj1, b, t0, tn);
    }
    if (j < n_pts)
        acc += pair_val(Pi, pts[j], b, t0, tn);
    return acc;
}

__global__ __launch_bounds__(NTHR) void cvm_main_kernel(
    const int2* __restrict__ idx, const float* __restrict__ t,
    const float4* __restrict__ pts,
    const float* __restrict__ t0p, const float* __restrict__ tnp,
    const float* __restrict__ betap,
    int n_events, int n_pts, double* __restrict__ partials) {

    const float b  = betap[0];
    const float t0 = t0p[0];
    const float tn = tnp[0];
    const int nblocks = gridDim.x;

    float accf = 0.0f;  // Sum(d_event) + Sum(integral); final = N*b - total

    // ---- Event part: grid-stride, coalesced idx/t stream, float4 gathers
    for (int e = blockIdx.x * NTHR + threadIdx.x; e < n_events;
         e += nblocks * NTHR) {
        int2 ij  = idx[e];
        float te = t[e];
        float4 pi = pts[ij.x];
        float4 pj = pts[ij.y];
        float dx = (pi.x - pj.x) + (pi.z - pj.z) * te;
        float dy = (pi.y - pj.y) + (pi.w - pj.w) * te;
        accf = fmaf(dx, dx, fmaf(dy, dy, accf));
    }

    // ---- Pair part: block b owns rows {b, n_rows-1-b} -> exactly n_pts pairs
    // per block (perfect balance, 2500 blocks = 9.8 waves/SIMD).
    const int n_rows = n_pts - 1;  // rows 0..n_pts-2 have pairs
    const int r1 = blockIdx.x;
    if (r1 < n_rows) {
        const int r2 = n_rows - 1 - r1;
        float4 Pi1 = pts[r1];
        accf += row_sweep(pts, Pi1, r1 + 1, n_pts, b, t0, tn);
        if (r2 > r1) {
            float4 Pi2 = pts[r2];
            accf += row_sweep(pts, Pi2, r2 + 1, n_pts, b, t0, tn);
        }
    }

    // ---- Block reduce (double), plain store — no atomics, no fences
    double v = (double)accf;
    #pragma unroll
    for (int off = 32; off > 0; off >>= 1) v += __shfl_down(v, off, 64);
    __shared__ double wsum[4];
    if ((threadIdx.x & 63) == 0) wsum[threadIdx.x >> 6] = v;
    __syncthreads();
    if (threadIdx.x == 0)
        partials[blockIdx.x] = wsum[0] + wsum[1] + wsum[2] + wsum[3];
}

__global__ void finish_kernel(const double* __restrict__ partials, int nblk,
                              const float* __restrict__ betap,
                              float* __restrict__ out, int n_events) {
    double v = 0.0;
    for (int i = threadIdx.x; i < nblk; i += NTHR) v += partials[i];
    #pragma unroll
    for (int off = 32; off > 0; off >>= 1) v += __shfl_down(v, off, 64);
    __shared__ double wsum[4];
    if ((threadIdx.x & 63) == 0) wsum[threadIdx.x >> 6] = v;
    __syncthreads();
    if (threadIdx.x == 0)
        out[0] = (float)((double)n_events * (double)betap[0] -
                         (wsum[0] + wsum[1] + wsum[2] + wsum[3]));
}

extern "C" void kernel_launch(void* const* d_in, const int* in_sizes, int n_in,
                              void* d_out, int out_size, void* d_ws, size_t ws_size,
                              hipStream_t stream) {
    const int2*  idx  = (const int2*)d_in[0];
    const float* t    = (const float*)d_in[1];
    const float* t0   = (const float*)d_in[2];
    const float* tn   = (const float*)d_in[3];
    const float* z0   = (const float*)d_in[4];
    const float* v0   = (const float*)d_in[5];
    const float* beta = (const float*)d_in[6];
    const int n_events = in_sizes[1];
    const int n_pts    = in_sizes[4] / 2;

    double* partials = (double*)d_ws;
    float4* pts = (float4*)((char*)d_ws + MAXBLK * sizeof(double));

    const int n_rows = n_pts - 1;
    int nblk = (n_rows + 1) / 2;          // 2500 for n_pts=5000
    if (nblk < 1) nblk = 1;
    if (nblk > MAXBLK) nblk = MAXBLK;

    pack_kernel<<<(n_pts + NTHR - 1) / NTHR, NTHR, 0, stream>>>(z0, v0, pts, n_pts);
    cvm_main_kernel<<<nblk, NTHR, 0, stream>>>(idx, t, pts, t0, tn, beta,
                                               n_events, n_pts, partials);
    finish_kernel<<<1, NTHR, 0, stream>>>(partials, nblk, beta,
                                          (float*)d_out, n_events);
}

// Round 8
// 99.957 us; speedup vs baseline: 1.0410x; 1.0239x over previous
//
#include <hip/hip_runtime.h>
#include <math.h>

#define NTHR 256
#define MAXBLK 4096

// ws layout: [0, MAXBLK*8) double partials; [MAXBLK*8, ...) float4 pts
// pts[p] = (z0x, z0y, v0x, v0y)

__global__ void pack_kernel(const float* __restrict__ z0,
                            const float* __restrict__ v0,
                            float4* __restrict__ pts, int n_pts) {
    int p = blockIdx.x * blockDim.x + threadIdx.x;
    if (p < n_pts)
        pts[p] = make_float4(z0[2 * p], z0[2 * p + 1], v0[2 * p], v0[2 * p + 1]);
}

// signed erf tail: sgn(x) * P(t(|x|)) * exp2(eL - x^2*log2e)
// (A&S 7.1.26: erf(x) = sgn(x)*(1 - P*exp(-x^2)), |err| <= 1.5e-7)
// HW-verified R3-R7 (absmax 0.0 vs np reference). DO NOT TOUCH.
__device__ __forceinline__ float erf_term(float x, float eL) {
    const float L2E = 1.4426950408889634f;
    float ax = fabsf(x);
    float tt = __builtin_amdgcn_rcpf(fmaf(0.3275911f, ax, 1.0f));
    float P = tt * fmaf(tt, fmaf(tt, fmaf(tt, fmaf(tt, 1.061405429f, -1.453152027f),
                        1.421413741f), -0.284496736f), 0.254829592f);
    float arg = fmaf(x * L2E, -x, eL);
    return copysignf(P * __builtin_amdgcn_exp2f(arg), x);
}

// integral term for one (i,j) pair; pref*exp folded into erf tails.
__device__ __forceinline__ float pair_val(float4 Pi, float4 Pj,
                                          float b, float t0, float tn) {
    const float SPI2 = 0.88622692545275801365f;  // sqrt(pi)/2
    const float L2E  = 1.4426950408889634f;
    float dzx = Pi.x - Pj.x, dzy = Pi.y - Pj.y;
    float dvx = Pi.z - Pj.z, dvy = Pi.w - Pj.w;
    float a2 = fmaf(dzx, dzx, dzy * dzy);
    float b2 = fmaf(dvx, dvx, dvy * dvy);
    float ab = fmaf(dzx, dvx, dzy * dvy);
    float r  = __builtin_amdgcn_rsqf(b2);      // 1/bnorm
    float mu = ab * (r * r);
    float e0 = fmaf(ab, mu, b - a2);           // in [b-a2, b] — exp never overflows
    float eL = e0 * L2E;
    float bn = b2 * r;
    float x1 = bn * (tn + mu);
    float x0 = bn * (t0 + mu);
    float pe1 = erf_term(x1, eL);
    float pe0 = erf_term(x0, eL);
    float jump = (x0 < 0.f && x1 >= 0.f)
                     ? 2.f * __builtin_amdgcn_exp2f(eL) : 0.f;
    return (SPI2 * r) * (jump + pe0 - pe1);
}

// j-sweep for one row: 2-way unrolled, both loads issued before either math
// chain. Identical to R7.
__device__ __forceinline__ float row_sweep(const float4* __restrict__ pts,
                                           float4 Pi, int jstart, int n_pts,
                                           float b, float t0, float tn) {
    float acc = 0.0f;
    int j = jstart + threadIdx.x;
    for (; j + NTHR < n_pts; j += 2 * NTHR) {
        float4 Pj0 = pts[j];
        float4 Pj1 = pts[j + NTHR];
        acc += pair_val(Pi, Pj0, b, t0, tn);
        acc += pair_val(Pi, Pj1, b, t0, tn);
    }
    if (j < n_pts)
        acc += pair_val(Pi, pts[j], b, t0, tn);
    return acc;
}

// Event part: 2 events per thread-iter. One int4 (two int2 indices) + one
// float2 load -> 4 independent gathers in flight per iteration (2x MLP).
__device__ __forceinline__ float event_sum(const int2* __restrict__ idx,
                                           const float* __restrict__ t,
                                           const float4* __restrict__ pts,
                                           int n_events, int nblocks) {
    const int4*   idx4 = (const int4*)idx;
    const float2* t2   = (const float2*)t;
    const int half = n_events >> 1;
    float acc = 0.0f;
    for (int h = blockIdx.x * NTHR + threadIdx.x; h < half;
         h += nblocks * NTHR) {
        int4 ij = idx4[h];            // events 2h (x,y) and 2h+1 (z,w)
        float2 tt = t2[h];
        float4 pi0 = pts[ij.x], pj0 = pts[ij.y];
        float4 pi1 = pts[ij.z], pj1 = pts[ij.w];
        float dx0 = (pi0.x - pj0.x) + (pi0.z - pj0.z) * tt.x;
        float dy0 = (pi0.y - pj0.y) + (pi0.w - pj0.w) * tt.x;
        float dx1 = (pi1.x - pj1.x) + (pi1.z - pj1.z) * tt.y;
        float dy1 = (pi1.y - pj1.y) + (pi1.w - pj1.w) * tt.y;
        acc = fmaf(dx0, dx0, fmaf(dy0, dy0, acc));
        acc = fmaf(dx1, dx1, fmaf(dy1, dy1, acc));
    }
    if ((n_events & 1) && blockIdx.x == 0 && threadIdx.x == 0) {
        int e = n_events - 1;
        int2 ij = idx[e];
        float te = t[e];
        float4 pi = pts[ij.x], pj = pts[ij.y];
        float dx = (pi.x - pj.x) + (pi.z - pj.z) * te;
        float dy = (pi.y - pj.y) + (pi.w - pj.w) * te;
        acc = fmaf(dx, dx, fmaf(dy, dy, acc));
    }
    return acc;
}

// Pair part: block b owns rows {b, n_rows-1-b} -> exactly n_pts pairs per
// block (perfect balance). Identical to R7.
__device__ __forceinline__ float pair_sum(const float4* __restrict__ pts,
                                          int n_pts, float b, float t0,
                                          float tn) {
    const int n_rows = n_pts - 1;
    const int r1 = blockIdx.x;
    float acc = 0.0f;
    if (r1 < n_rows) {
        const int r2 = n_rows - 1 - r1;
        float4 Pi1 = pts[r1];
        acc += row_sweep(pts, Pi1, r1 + 1, n_pts, b, t0, tn);
        if (r2 > r1) {
            float4 Pi2 = pts[r2];
            acc += row_sweep(pts, Pi2, r2 + 1, n_pts, b, t0, tn);
        }
    }
    return acc;
}

__global__ __launch_bounds__(NTHR) void cvm_main_kernel(
    const int2* __restrict__ idx, const float* __restrict__ t,
    const float4* __restrict__ pts,
    const float* __restrict__ t0p, const float* __restrict__ tnp,
    const float* __restrict__ betap,
    int n_events, int n_pts, double* __restrict__ partials) {

    const float b  = betap[0];
    const float t0 = t0p[0];
    const float tn = tnp[0];
    const int nblocks = gridDim.x;

    // PHASE PARITY: even blocks run events->pairs, odd blocks pairs->events.
    // At any instant ~half the resident waves are in the issue-bound pair
    // phase, covering the gather-latency stalls of the event-phase waves
    // (R2-R7 ran all waves through the stally event phase simultaneously).
    float accf;
    if (blockIdx.x & 1) {
        accf = pair_sum(pts, n_pts, b, t0, tn);
        accf += event_sum(idx, t, pts, n_events, nblocks);
    } else {
        accf = event_sum(idx, t, pts, n_events, nblocks);
        accf += pair_sum(pts, n_pts, b, t0, tn);
    }

    // ---- Block reduce (double), plain store — no atomics, no fences
    double v = (double)accf;
    #pragma unroll
    for (int off = 32; off > 0; off >>= 1) v += __shfl_down(v, off, 64);
    __shared__ double wsum[4];
    if ((threadIdx.x & 63) == 0) wsum[threadIdx.x >> 6] = v;
    __syncthreads();
    if (threadIdx.x == 0)
        partials[blockIdx.x] = wsum[0] + wsum[1] + wsum[2] + wsum[3];
}

__global__ void finish_kernel(const double* __restrict__ partials, int nblk,
                              const float* __restrict__ betap,
                              float* __restrict__ out, int n_events) {
    double v = 0.0;
    for (int i = threadIdx.x; i < nblk; i += NTHR) v += partials[i];
    #pragma unroll
    for (int off = 32; off > 0; off >>= 1) v += __shfl_down(v, off, 64);
    __shared__ double wsum[4];
    if ((threadIdx.x & 63) == 0) wsum[threadIdx.x >> 6] = v;
    __syncthreads();
    if (threadIdx.x == 0)
        out[0] = (float)((double)n_events * (double)betap[0] -
                         (wsum[0] + wsum[1] + wsum[2] + wsum[3]));
}

extern "C" void kernel_launch(void* const* d_in, const int* in_sizes, int n_in,
                              void* d_out, int out_size, void* d_ws, size_t ws_size,
                              hipStream_t stream) {
    const int2*  idx  = (const int2*)d_in[0];
    const float* t    = (const float*)d_in[1];
    const float* t0   = (const float*)d_in[2];
    const float* tn   = (const float*)d_in[3];
    const float* z0   = (const float*)d_in[4];
    const float* v0   = (const float*)d_in[5];
    const float* beta = (const float*)d_in[6];
    const int n_events = in_sizes[1];
    const int n_pts    = in_sizes[4] / 2;

    double* partials = (double*)d_ws;
    float4* pts = (float4*)((char*)d_ws + MAXBLK * sizeof(double));

    const int n_rows = n_pts - 1;
    int nblk = (n_rows + 1) / 2;          // 2500 for n_pts=5000
    if (nblk < 1) nblk = 1;
    if (nblk > MAXBLK) nblk = MAXBLK;

    pack_kernel<<<(n_pts + NTHR - 1) / NTHR, NTHR, 0, stream>>>(z0, v0, pts, n_pts);
    cvm_main_kernel<<<nblk, NTHR, 0, stream>>>(idx, t, pts, t0, tn, beta,
                                               n_events, n_pts, partials);
    finish_kernel<<<1, NTHR, 0, stream>>>(partials, nblk, beta,
                                          (float*)d_out, n_events);
}